// Round 11
// baseline (295.764 us; speedup 1.0000x reference)
//
#include <hip/hip_runtime.h>
#include <hip/hip_bf16.h>

#define N_    64
#define C_    64      // C_in == C_out
#define T_    300
#define V_    25
#define K_    3
#define KT_   9
#define PAD_  4

typedef short bf16x8 __attribute__((ext_vector_type(8)));
typedef float f32x4  __attribute__((ext_vector_type(4)));

static __device__ __forceinline__ unsigned short f2bf(float f) {
    __hip_bfloat16 h = __float2bfloat16(f);
    return __builtin_bit_cast(unsigned short, h);
}
static __device__ __forceinline__ unsigned int pk2(float a, float b) {
    return (unsigned int)f2bf(a) | ((unsigned int)f2bf(b) << 16);
}
static __device__ __forceinline__ float bfhi(unsigned int u) {   // low bf16 -> f32
    return __builtin_bit_cast(float, u << 16);
}
static __device__ __forceinline__ float bflo(unsigned int u) {   // high bf16 -> f32
    return __builtin_bit_cast(float, u & 0xffff0000u);
}
static __device__ __forceinline__ float bf2f(unsigned short u) {
    return __builtin_bit_cast(float, (unsigned int)u << 16);
}

// ---------------------------------------------------------------------------
// prep: weight tables (bf16, MFMA layouts) + fused GCN bias table.
// ---------------------------------------------------------------------------
__global__ __launch_bounds__(256) void prep_kernel(
    const float* __restrict__ Wt, const float* __restrict__ Wg,
    const float* __restrict__ bg, const float* __restrict__ A,
    unsigned short* __restrict__ Wtb, unsigned short* __restrict__ Wgbt,
    unsigned short* __restrict__ bias2b, unsigned short* __restrict__ Abt)
{
    int i = blockIdx.x * 256 + threadIdx.x;
    if (i < 9*64*64) {
        int kt = i >> 12, r = i & 4095, o = r >> 6, c = r & 63;
        Wtb[i] = f2bf(Wt[(size_t)(o*64 + c)*9 + kt]);
    }
    int j = i - 9*64*64;
    if (j >= 0 && j < 64*192) {
        int o = j / 192, kc = j - 192*(j/192);
        int k = kc >> 6, ci = kc & 63;
        Wgbt[j] = f2bf(Wg[(size_t)(k*64 + o)*64 + ci]);
    }
    int m = j - 64*192;
    if (m >= 0 && m < 64*25) {
        int c = m / 25, w = m - 25*(m/25);
        float s = 0.f;
        for (int k = 0; k < 3; ++k) {
            float col = 0.f;
            for (int v = 0; v < 25; ++v) col += A[k*625 + v*25 + w];
            s += bg[k*64 + c] * col;
        }
        bias2b[w*64 + c] = f2bf(s);
    }
    int p = m - 64*25;
    if (p >= 0 && p < 3*32*40) {
        int k = p / 1280, r = p - 1280*k, w = r / 40, v = r - 40*(r/40);
        float val = (w < 25 && v < 25) ? A[k*625 + v*25 + w] : 0.f;
        Abt[p] = f2bf(val);
    }
}

// ---------------------------------------------------------------------------
// FUSED gcn+tcn: per (n, 20-t tile), 512 threads (8 waves), 960 blocks,
// XCD-chunk swizzled. gcn computes y2 for the tile + 4-t halo each side
// (28 t) directly into an LDS slab in tcn's [col][64ch] XOR-swizzled
// fragment layout; tcn then runs barrier-free from LDS. y2 never in HBM.
//  - gcn waves: (tp = t-parity of pair, blk): stage1 ci-block / stage2 o-block
//  - tcn waves: wave owns 64 output cols x all 64 o (acc[4][4] = 64 VGPR)
// ---------------------------------------------------------------------------
#define FTT    20               // output t per block
#define FSLABC 712              // 28t*25 = 700 cols + 12 overrun pad
#define FNBLK  (N_*(T_/FTT))    // 960

template<int BF>
__global__ __launch_bounds__(512, 2) void fused_kernel(
    const float* __restrict__ x,
    const unsigned short* __restrict__ Wgbt,
    const unsigned short* __restrict__ Abt,
    const unsigned short* __restrict__ bias2b,
    const unsigned short* __restrict__ Wtb,
    const float* __restrict__ bt,
    unsigned short* __restrict__ y3b, float* __restrict__ y3f,
    float* __restrict__ psum, float* __restrict__ psq)
{
    __shared__ unsigned short slab[FSLABC*64];   // y2 [lc][64ch] swz, 91136 B
    __shared__ unsigned short xa[64*200];        // [tp*32+w][200], 25600 B
    __shared__ unsigned short xslab[128*40];     // [tp*64+ci][40], 10240 B
    __shared__ unsigned int   bias2L[25*34];     // 3400 B
    __shared__ float s_sum[64], s_sq[64];

    const int tid  = threadIdx.x;
    // XCD-chunk swizzle: each XCD gets 120 consecutive logical blocks
    const int bid  = (int)((blockIdx.x & 7)*120 + (blockIdx.x >> 3));
    const int n    = bid / (T_/FTT);
    const int tg   = (bid % (T_/FTT)) * FTT;
    const int lane = tid & 63, wave = tid >> 6;
    const int l15  = lane & 15, lq = lane >> 4;
    const int tp   = wave & 1, blk = wave >> 1;

    const int t_begin = (tg >= PAD_) ? (tg - PAD_) : 0;
    const int t_end   = (tg + FTT + PAD_ <= T_) ? (tg + FTT + PAD_) : T_;
    const int P = (t_end - t_begin) >> 1;        // 12 or 14 pairs (count even)

    // pinned gcn weights (once per block)
    bf16x8 wfrag[6], afrag[6];
    #pragma unroll
    for (int cb = 0; cb < 6; ++cb) {
        wfrag[cb] = *(const bf16x8*)(Wgbt + (blk*16 + l15)*192 + cb*32 + lq*8);
        asm volatile("" : "+v"(wfrag[cb]));
    }
    #pragma unroll
    for (int s = 0; s < 6; ++s) {
        afrag[s] = *(const bf16x8*)(Abt + ((s >> 1)*32 + (s & 1)*16 + l15)*40 + lq*8);
        asm volatile("" : "+v"(afrag[s]));
    }

    // init LDS: zero slab (uncomputed cols = conv zero-padding), bias, xslab
    for (int i = tid; i < FSLABC*16; i += 512)
        ((unsigned long long*)slab)[i] = 0ull;
    for (int i = tid; i < 800; i += 512)
        bias2L[(i >> 5)*34 + (i & 31)] = ((const unsigned int*)bias2b)[i];
    if (tid < 128*3) {
        int row = tid / 3, z = tid - 3*(tid/3);
        ((unsigned int*)xslab)[row*20 + 13 + z] = 0u;
    }
    // fill xslab with pair 0 (t = t_begin + tp)
    #pragma unroll
    for (int s = 0; s < 4; ++s) {
        int slot = tid + s*512;
        if (slot < 128*13) {
            int row = slot/13, sl = slot - 13*row;
            int tpp = row >> 6, ci = row & 63;
            const float* xr = x + ((size_t)(n*C_ + ci)*T_ + t_begin + tpp)*V_;
            float f0, f1;
            if (sl < 12) { float2 t2 = *(const float2*)(xr + 2*sl); f0 = t2.x; f1 = t2.y; }
            else         { f0 = xr[24]; f1 = 0.f; }
            ((unsigned int*)xslab)[row*20 + sl] = pk2(f0, f1);
        }
    }
    __syncthreads();

    // ================= GCN phase: P pairs of t =================
    for (int p = 0; p < P; ++p) {
        const bool hn = (p + 1 < P);
        float2 Lr[4];
        if (hn) {
            #pragma unroll
            for (int s = 0; s < 4; ++s) {
                int slot = tid + s*512;
                if (slot < 128*13) {
                    int row = slot/13, sl = slot - 13*row;
                    int tpp = row >> 6, ci = row & 63;
                    const float* xr = x + ((size_t)(n*C_ + ci)*T_
                                           + t_begin + 2*(p+1) + tpp)*V_;
                    if (sl < 12) Lr[s] = *(const float2*)(xr + 2*sl);
                    else         { Lr[s].x = xr[24]; Lr[s].y = 0.f; }
                }
            }
        }
        // stage1: wave (tp, ci-block = blk): xa[tp*32+w][k*64+ci]
        {
            bf16x8 xf = *(const bf16x8*)(xslab + (tp*64 + blk*16 + l15)*40 + lq*8);
            #pragma unroll
            for (int s = 0; s < 6; ++s) {
                f32x4 d = {};
                d = __builtin_amdgcn_mfma_f32_16x16x32_bf16(xf, afrag[s], d, 0, 0, 0);
                const int w = (s & 1)*16 + l15;
                if (w < 25) {
                    const int k = s >> 1;
                    unsigned long long pv = (unsigned long long)pk2(d[0], d[1])
                                          | ((unsigned long long)pk2(d[2], d[3]) << 32);
                    *(unsigned long long*)((char*)xa + (tp*32 + w)*400
                                           + k*128 + blk*32 + lq*8) = pv;
                }
            }
        }
        __syncthreads();
        // stage2: wave (tp, o-block = blk) -> slab[lc][o], XOR-swizzled
        {
            const int t = t_begin + 2*p + tp;
            f32x4 acc0 = {}, acc1 = {};
            #pragma unroll
            for (int cb = 0; cb < 6; ++cb) {
                bf16x8 b0 = *(const bf16x8*)((const char*)xa
                              + (tp*32 + l15)*400 + cb*64 + lq*16);
                bf16x8 b1 = *(const bf16x8*)((const char*)xa
                              + (tp*32 + 16 + l15)*400 + cb*64 + lq*16);
                acc0 = __builtin_amdgcn_mfma_f32_16x16x32_bf16(wfrag[cb], b0, acc0, 0, 0, 0);
                acc1 = __builtin_amdgcn_mfma_f32_16x16x32_bf16(wfrag[cb], b1, acc1, 0, 0, 0);
            }
            const int lcb = (t - tg + PAD_)*25;
            const int o0  = blk*16 + lq*4;
            {
                const int lc = lcb + l15;
                unsigned int bu0 = bias2L[l15*34 + (o0 >> 1)];
                unsigned int bu1 = bias2L[l15*34 + (o0 >> 1) + 1];
                float v0 = acc0[0] + bfhi(bu0), v1 = acc0[1] + bflo(bu0);
                float v2 = acc0[2] + bfhi(bu1), v3 = acc0[3] + bflo(bu1);
                unsigned long long pv = (unsigned long long)pk2(v0, v1)
                                      | ((unsigned long long)pk2(v2, v3) << 32);
                int byte = (lc*128 + o0*2) ^ ((lc & 7) << 4);
                *(unsigned long long*)((char*)slab + byte) = pv;
            }
            if (l15 < 9) {
                const int lc = lcb + 16 + l15;
                unsigned int bu0 = bias2L[(16 + l15)*34 + (o0 >> 1)];
                unsigned int bu1 = bias2L[(16 + l15)*34 + (o0 >> 1) + 1];
                float v0 = acc1[0] + bfhi(bu0), v1 = acc1[1] + bflo(bu0);
                float v2 = acc1[2] + bfhi(bu1), v3 = acc1[3] + bflo(bu1);
                unsigned long long pv = (unsigned long long)pk2(v0, v1)
                                      | ((unsigned long long)pk2(v2, v3) << 32);
                int byte = (lc*128 + o0*2) ^ ((lc & 7) << 4);
                *(unsigned long long*)((char*)slab + byte) = pv;
            }
        }
        // write prefetched pair into xslab (stage1 readers done at barrier)
        if (hn) {
            #pragma unroll
            for (int s = 0; s < 4; ++s) {
                int slot = tid + s*512;
                if (slot < 128*13) {
                    int row = slot/13, sl = slot - 13*row;
                    ((unsigned int*)xslab)[row*20 + sl] = pk2(Lr[s].x, Lr[s].y);
                }
            }
        }
        __syncthreads();
    }

    // ================= TCN phase (LDS slab, no barriers) =================
    f32x4 acc[4][4] = {};
    #pragma unroll
    for (int kt = 0; kt < 9; ++kt) {
        #pragma unroll
        for (int cb = 0; cb < 2; ++cb) {
            bf16x8 a[4];
            #pragma unroll
            for (int mt = 0; mt < 4; ++mt)
                a[mt] = *(const bf16x8*)(Wtb + kt*4096 + (mt*16 + l15)*64
                                         + cb*32 + lq*8);
            #pragma unroll
            for (int nf = 0; nf < 4; ++nf) {
                const int lc = wave*64 + nf*16 + l15 + kt*25;   // <= 711
                int byte = (lc*128 + cb*64 + lq*16) ^ ((lc & 7) << 4);
                bf16x8 b = *(const bf16x8*)((const char*)slab + byte);
                #pragma unroll
                for (int mt = 0; mt < 4; ++mt)
                    acc[mt][nf] = __builtin_amdgcn_mfma_f32_16x16x32_bf16(
                        a[mt], b, acc[mt][nf], 0, 0, 0);
            }
        }
    }

    // epilogue: bias + y3 store + BN partials
    float ls[16], lsq[16];
    #pragma unroll
    for (int e = 0; e < 16; ++e) { ls[e] = 0.f; lsq[e] = 0.f; }
    #pragma unroll
    for (int mt = 0; mt < 4; ++mt) {
        #pragma unroll
        for (int r = 0; r < 4; ++r) {
            const int e = mt*4 + r;
            const int o = mt*16 + lq*4 + r;
            const float bias = bt[o];
            #pragma unroll
            for (int nf = 0; nf < 4; ++nf) {
                const int col = wave*64 + nf*16 + l15;
                if (col < FTT*V_) {
                    const float val = acc[mt][nf][r] + bias;
                    const size_t idx = (size_t)(n*C_ + o)*(T_*V_) + tg*V_ + col;
                    if (BF) y3b[idx] = f2bf(val);
                    else    y3f[idx] = val;
                    ls[e] += val; lsq[e] += val*val;
                }
            }
        }
    }

    if (tid < 64) { s_sum[tid] = 0.f; s_sq[tid] = 0.f; }
    __syncthreads();
    #pragma unroll
    for (int e = 0; e < 16; ++e) {
        float a = ls[e], b = lsq[e];
        a += __shfl_xor(a, 1); a += __shfl_xor(a, 2);
        a += __shfl_xor(a, 4); a += __shfl_xor(a, 8);
        b += __shfl_xor(b, 1); b += __shfl_xor(b, 2);
        b += __shfl_xor(b, 4); b += __shfl_xor(b, 8);
        if (l15 == 0) {
            const int o = (e >> 2)*16 + lq*4 + (e & 3);
            atomicAdd(&s_sum[o], a);
            atomicAdd(&s_sq[o], b);
        }
    }
    __syncthreads();
    if (tid < 64) {
        psum[(size_t)tid*FNBLK + bid] = s_sum[tid];
        psq [(size_t)tid*FNBLK + bid] = s_sq [tid];
    }
}

// ---------------------------------------------------------------------------
// stats: reduce partials -> per-channel scale/shift
// ---------------------------------------------------------------------------
__global__ __launch_bounds__(256) void stats_kernel(
    const float* __restrict__ psum, const float* __restrict__ psq,
    const float* __restrict__ gamma, const float* __restrict__ beta,
    float* __restrict__ sb)
{
    const int o = blockIdx.x;
    const int tid = threadIdx.x;
    float s = 0.f, q = 0.f;
    for (int i = tid; i < FNBLK; i += 256) {
        s += psum[(size_t)o*FNBLK + i];
        q += psq [(size_t)o*FNBLK + i];
    }
    __shared__ float rs[256], rq[256];
    rs[tid] = s; rq[tid] = q;
    __syncthreads();
    for (int off = 128; off > 0; off >>= 1) {
        if (tid < off) { rs[tid] += rs[tid + off]; rq[tid] += rq[tid + off]; }
        __syncthreads();
    }
    if (tid == 0) {
        const float cnt = (float)(N_ * T_ * V_);
        float mean = rs[0] / cnt;
        float var  = rq[0] / cnt - mean * mean;
        float rstd = rsqrtf(var + 1e-5f);
        float sc   = gamma[o] * rstd;
        sb[o]      = sc;
        sb[C_ + o] = beta[o] - mean * sc;
    }
}

// ---------------------------------------------------------------------------
// BN + residual + ReLU
// ---------------------------------------------------------------------------
__global__ __launch_bounds__(256) void bn_res_relu_bf16_kernel(
    const float* __restrict__ x, const unsigned short* __restrict__ y3b,
    const float* __restrict__ sb, float* __restrict__ out)
{
    const size_t total4 = (size_t)N_ * C_ * T_ * V_ / 4;  // 7,680,000
    size_t i4 = (size_t)blockIdx.x * 256 + threadIdx.x;
    if (i4 >= total4) return;
    const int c = (int)((i4 / (T_ * V_ / 4)) % C_);
    const float sc = sb[c], sh = sb[C_ + c];
    ushort4 yv = ((const ushort4*)y3b)[i4];
    float4 xv = ((const float4*)x)[i4];
    float4 o;
    o.x = fmaxf(bf2f(yv.x) * sc + sh + xv.x, 0.0f);
    o.y = fmaxf(bf2f(yv.y) * sc + sh + xv.y, 0.0f);
    o.z = fmaxf(bf2f(yv.z) * sc + sh + xv.z, 0.0f);
    o.w = fmaxf(bf2f(yv.w) * sc + sh + xv.w, 0.0f);
    ((float4*)out)[i4] = o;
}

__global__ __launch_bounds__(256) void bn_res_relu_f32_kernel(
    const float* __restrict__ x, const float* __restrict__ sb,
    float* __restrict__ y)
{
    const size_t total4 = (size_t)N_ * C_ * T_ * V_ / 4;
    size_t i4 = (size_t)blockIdx.x * 256 + threadIdx.x;
    if (i4 >= total4) return;
    const int c = (int)((i4 / (T_ * V_ / 4)) % C_);
    const float sc = sb[c], sh = sb[C_ + c];
    float4 yv = ((const float4*)y)[i4];
    float4 xv = ((const float4*)x)[i4];
    float4 o;
    o.x = fmaxf(yv.x * sc + sh + xv.x, 0.0f);
    o.y = fmaxf(yv.y * sc + sh + xv.y, 0.0f);
    o.z = fmaxf(yv.z * sc + sh + xv.z, 0.0f);
    o.w = fmaxf(yv.w * sc + sh + xv.w, 0.0f);
    ((float4*)y)[i4] = o;
}

// ---------------------------------------------------------------------------
extern "C" void kernel_launch(void* const* d_in, const int* in_sizes, int n_in,
                              void* d_out, int out_size, void* d_ws, size_t ws_size,
                              hipStream_t stream)
{
    const float* x     = (const float*)d_in[0];
    const float* A     = (const float*)d_in[1];
    const float* wg    = (const float*)d_in[2];
    const float* bg    = (const float*)d_in[3];
    const float* wt    = (const float*)d_in[4];
    const float* bt    = (const float*)d_in[5];
    const float* gamma = (const float*)d_in[6];
    const float* beta  = (const float*)d_in[7];
    float* out = (float*)d_out;

    char* wsb = (char*)d_ws;
    const size_t Y3B   = 61440000;                 // y3 bf16 (optional)
    const size_t PSB   = (size_t)C_ * FNBLK * 4;   // 245,760 each
    const size_t TABLE = 2*PSB + 512 + 73728 + 24576 + 3200 + 7680;
    const bool usebf = ws_size >= Y3B + TABLE;

    unsigned short* y3b = (unsigned short*)wsb;
    const size_t base2  = usebf ? Y3B : 0;
    float* psum            = (float*)(wsb + base2);
    float* psq             = (float*)(wsb + base2 + PSB);
    float* sb              = (float*)(wsb + base2 + 2*PSB);
    unsigned short* Wtb    = (unsigned short*)(wsb + base2 + 2*PSB + 512);
    unsigned short* Wgbt   = (unsigned short*)(wsb + base2 + 2*PSB + 512 + 73728);
    unsigned short* bias2b = (unsigned short*)(wsb + base2 + 2*PSB + 512 + 73728 + 24576);
    unsigned short* Abt    = (unsigned short*)(wsb + base2 + 2*PSB + 512 + 73728 + 24576 + 3200);

    prep_kernel<<<214, 256, 0, stream>>>(wt, wg, bg, A, Wtb, Wgbt, bias2b, Abt);
    if (usebf)
        fused_kernel<1><<<FNBLK, 512, 0, stream>>>(x, Wgbt, Abt, bias2b, Wtb, bt,
                                                   y3b, out, psum, psq);
    else
        fused_kernel<0><<<FNBLK, 512, 0, stream>>>(x, Wgbt, Abt, bias2b, Wtb, bt,
                                                   y3b, out, psum, psq);
    stats_kernel<<<C_, 256, 0, stream>>>(psum, psq, gamma, beta, sb);
    const size_t total4 = (size_t)N_ * C_ * T_ * V_ / 4;
    const int bnblk = (int)((total4 + 255) / 256);
    if (usebf)
        bn_res_relu_bf16_kernel<<<bnblk, 256, 0, stream>>>(x, y3b, sb, out);
    else
        bn_res_relu_f32_kernel<<<bnblk, 256, 0, stream>>>(x, sb, out);
}